// Round 4
// baseline (1265.053 us; speedup 1.0000x reference)
//
#include <hip/hip_runtime.h>

namespace {

constexpr int S_LEN  = 2048;
constexpr int H_N    = 8;
constexpr int D_DIM  = 64;
constexpr int N_DIM  = 32;
constexpr int WAVES  = 8;                    // waves per block
constexpr int TW     = 16;                   // timesteps per wave
constexpr int CHUNK  = WAVES * TW;           // 128 timesteps per block
constexpr int NCHUNK = S_LEN / CHUNK;        // 16 chunks per (b,h)
constexpr int NBH    = 16;                   // b*h pairs
constexpr float NLOG2E = -1.4426950408889634f;

// ws: [0,1KB) flags (zeroed each launch), [4KB,...) hbuf: 256 slots x 2048 floats.
// Block bid = bh*16 + k. Block k>0 spin-waits on flags[bid] set by block bid-1,
// which publishes the sequential state h entering chunk k (layout [d][n]).

__global__ __launch_bounds__(512, 2) void ssm_fused(
    const float* __restrict__ up,  const float* __restrict__ dtp,
    const float* __restrict__ Ap,  const float* __restrict__ Bp,
    const float* __restrict__ Cp,  const float* __restrict__ Dp,
    float* __restrict__ outp, unsigned int* __restrict__ flags,
    float* __restrict__ hbuf)
{
    __shared__ float2 buf[D_DIM * 33];       // [d][n] padded: 2-way bank alias only

    const int w    = threadIdx.x >> 6;
    const int lane = threadIdx.x & 63;
    const int bid  = blockIdx.x;
    const int bh   = bid >> 4;
    const int k    = bid & 15;
    const int b = bh >> 3, hh = bh & 7;
    const int d = lane;

    const float* Arow = Ap + (hh * D_DIM + d) * N_DIM;
    float Aneg[N_DIM];
#pragma unroll
    for (int n = 0; n < N_DIM; ++n) Aneg[n] = NLOG2E * Arow[n];

    const int base_ud = b * (S_LEN * H_N * D_DIM) + hh * D_DIM + d;
    const int base_bc = b * (S_LEN * H_N * N_DIM) + hh * N_DIM;
    const int s0 = k * CHUNK + w * TW;

    // ---- phase A: local chunk transform (aP, bA) over my 16 timesteps ----
    float aP[N_DIM], bA[N_DIM];
#pragma unroll
    for (int n = 0; n < N_DIM; ++n) { aP[n] = 1.0f; bA[n] = 0.0f; }

#pragma unroll 2
    for (int t = 0; t < TW; ++t) {
        const int s = s0 + t;
        const float dtv = dtp[base_ud + s * (H_N * D_DIM)];
        const float uv  = up [base_ud + s * (H_N * D_DIM)];
        const float kk  = dtv * uv;
        const int sbc = __builtin_amdgcn_readfirstlane(base_bc + s * (H_N * N_DIM));
        const float4* B4 = reinterpret_cast<const float4*>(Bp + sbc);
        float Br[N_DIM];
#pragma unroll
        for (int j = 0; j < 8; ++j) {
            float4 v = B4[j];
            Br[4*j+0] = v.x; Br[4*j+1] = v.y; Br[4*j+2] = v.z; Br[4*j+3] = v.w;
        }
#pragma unroll
        for (int n = 0; n < N_DIM; ++n) {
            const float e = __builtin_amdgcn_exp2f(dtv * Aneg[n]);
            aP[n] = aP[n] * e;
            bA[n] = fmaf(e, bA[n], kk * Br[n]);
        }
    }

    // ---- in-block ripple: exclusive prefix transform (Pa,Pb) per wave ----
    float Pa[N_DIM], Pb[N_DIM];
#pragma unroll
    for (int n = 0; n < N_DIM; ++n) { Pa[n] = 1.0f; Pb[n] = 0.0f; }

    for (int stepw = 0; stepw < WAVES; ++stepw) {
        if (w == stepw) {
            if (w > 0) {
#pragma unroll
                for (int n = 0; n < N_DIM; ++n) {
                    float2 g = buf[d * 33 + n];
                    Pa[n] = g.x; Pb[n] = g.y;
                }
            }
            if (w < WAVES - 1) {
#pragma unroll
                for (int n = 0; n < N_DIM; ++n) {
                    buf[d * 33 + n] = make_float2(aP[n] * Pa[n],
                                                  fmaf(aP[n], Pb[n], bA[n]));
                }
            }
        }
        __syncthreads();
    }

    // ---- chained cross-block scan: wait for incoming state ----
    float hin[N_DIM];
    if (k > 0) {
        if (threadIdx.x == 0) {
            while (__hip_atomic_load(flags + bid, __ATOMIC_ACQUIRE,
                                     __HIP_MEMORY_SCOPE_AGENT) == 0u)
                __builtin_amdgcn_s_sleep(8);
        }
        __syncthreads();
        float* hp = hbuf + (size_t)bid * 2048 + d * N_DIM;
#pragma unroll
        for (int n = 0; n < N_DIM; ++n)
            hin[n] = __hip_atomic_load(hp + n, __ATOMIC_RELAXED,
                                       __HIP_MEMORY_SCOPE_AGENT);
    } else {
#pragma unroll
        for (int n = 0; n < N_DIM; ++n) hin[n] = 0.0f;
    }

    // ---- publish outgoing state (wave 7 only) ----
    if (w == WAVES - 1 && k < NCHUNK - 1) {
        float* hq = hbuf + (size_t)(bid + 1) * 2048 + d * N_DIM;
#pragma unroll
        for (int n = 0; n < N_DIM; ++n) {
            const float Ta = aP[n] * Pa[n];
            const float Tb = fmaf(aP[n], Pb[n], bA[n]);
            __hip_atomic_store(hq + n, fmaf(Ta, hin[n], Tb),
                               __ATOMIC_RELAXED, __HIP_MEMORY_SCOPE_AGENT);
        }
        __threadfence();
        if (lane == 0)
            __hip_atomic_store(flags + bid + 1, 1u, __ATOMIC_RELEASE,
                               __HIP_MEMORY_SCOPE_AGENT);
    }

    // ---- phase C: rescan my 16 timesteps from my wave's entering state ----
    float h[N_DIM];
#pragma unroll
    for (int n = 0; n < N_DIM; ++n) h[n] = fmaf(Pa[n], hin[n], Pb[n]);

    const float Dv = Dp[hh];

#pragma unroll 2
    for (int t = 0; t < TW; ++t) {
        const int s = s0 + t;
        const float dtv = dtp[base_ud + s * (H_N * D_DIM)];
        const float uv  = up [base_ud + s * (H_N * D_DIM)];
        const float kk  = dtv * uv;
        const int sbc = __builtin_amdgcn_readfirstlane(base_bc + s * (H_N * N_DIM));
        const float4* B4 = reinterpret_cast<const float4*>(Bp + sbc);
        const float4* C4 = reinterpret_cast<const float4*>(Cp + sbc);
        float Br[N_DIM], Cr[N_DIM];
#pragma unroll
        for (int j = 0; j < 8; ++j) {
            float4 v = B4[j];
            Br[4*j+0] = v.x; Br[4*j+1] = v.y; Br[4*j+2] = v.z; Br[4*j+3] = v.w;
            float4 c = C4[j];
            Cr[4*j+0] = c.x; Cr[4*j+1] = c.y; Cr[4*j+2] = c.z; Cr[4*j+3] = c.w;
        }
        float y0 = 0.0f, y1 = 0.0f, y2 = 0.0f, y3 = 0.0f;
#pragma unroll
        for (int n = 0; n < N_DIM; ++n) {
            const float e = __builtin_amdgcn_exp2f(dtv * Aneg[n]);
            h[n] = fmaf(e, h[n], kk * Br[n]);
            if ((n & 3) == 0)      y0 = fmaf(h[n], Cr[n], y0);
            else if ((n & 3) == 1) y1 = fmaf(h[n], Cr[n], y1);
            else if ((n & 3) == 2) y2 = fmaf(h[n], Cr[n], y2);
            else                   y3 = fmaf(h[n], Cr[n], y3);
        }
        outp[base_ud + s * (H_N * D_DIM)] = fmaf(Dv, uv, (y0 + y1) + (y2 + y3));
    }
}

} // namespace

extern "C" void kernel_launch(void* const* d_in, const int* in_sizes, int n_in,
                              void* d_out, int out_size, void* d_ws, size_t ws_size,
                              hipStream_t stream)
{
    const float* u  = (const float*)d_in[0];
    const float* dt = (const float*)d_in[1];
    const float* A  = (const float*)d_in[2];
    const float* B  = (const float*)d_in[3];
    const float* C  = (const float*)d_in[4];
    const float* D  = (const float*)d_in[5];
    float* out = (float*)d_out;

    unsigned int* flags = (unsigned int*)d_ws;
    float* hbuf = (float*)((char*)d_ws + 4096);

    hipMemsetAsync(d_ws, 0, 4096, stream);   // reset chain flags every launch/replay
    ssm_fused<<<dim3(NBH * NCHUNK), dim3(512), 0, stream>>>(
        u, dt, A, B, C, D, out, flags, hbuf);
}

// Round 5
// 142.288 us; speedup vs baseline: 8.8908x; 8.8908x over previous
//
#include <hip/hip_runtime.h>
#include <hip/hip_cooperative_groups.h>

namespace cg = cooperative_groups;

namespace {

constexpr int S_LEN  = 2048;
constexpr int H_N    = 8;
constexpr int D_DIM  = 64;
constexpr int N_DIM  = 32;
constexpr int NC     = 128;              // chunks per (b,h) sequence
constexpr int L_CH   = S_LEN / NC;       // 16 timesteps per chunk
constexpr float NLOG2E = -1.4426950408889634f;

// ws layout:
//   agg : [chunk][slot 0..63][ch 0..1023]  slot n = aProd[n], 32+n = bAgg[n]
//   pref: [chunk][n 0..31 ][ch 0..1023]    prefix state entering chunk
// Wave unit W = blockIdx.x*8 + w ; bh = W & 15 ; chunk = W >> 4.

__global__ __launch_bounds__(512, 2) void ssm_coop(
    const float* __restrict__ up,  const float* __restrict__ dtp,
    const float* __restrict__ Ap,  const float* __restrict__ Bp,
    const float* __restrict__ Cp,  const float* __restrict__ Dp,
    float* __restrict__ outp,
    float* __restrict__ agg, float* __restrict__ pref)
{
    const int w    = threadIdx.x >> 6;
    const int lane = threadIdx.x & 63;
    const int W    = blockIdx.x * 8 + w;
    const int bh    = __builtin_amdgcn_readfirstlane(W & 15);
    const int chunk = __builtin_amdgcn_readfirstlane(W >> 4);
    const int b = bh >> 3, hh = bh & 7;
    const int d = lane;
    const int ch = bh * 64 + d;

    const float* Arow = Ap + (hh * D_DIM + d) * N_DIM;
    float Aneg[N_DIM];
#pragma unroll
    for (int n = 0; n < N_DIM; ++n) Aneg[n] = NLOG2E * Arow[n];

    const int base_ud = b * (S_LEN * H_N * D_DIM) + hh * D_DIM + d;
    const int base_bc = b * (S_LEN * H_N * N_DIM) + hh * N_DIM;
    const int s0 = chunk * L_CH;

    // ---------------- phase A: per-chunk transform (aP, bA) ----------------
    float aP[N_DIM], bA[N_DIM];
#pragma unroll
    for (int n = 0; n < N_DIM; ++n) { aP[n] = 1.0f; bA[n] = 0.0f; }

#pragma unroll 2
    for (int t = 0; t < L_CH; ++t) {
        const int s = s0 + t;
        const float dtv = dtp[base_ud + s * (H_N * D_DIM)];
        const float uv  = up [base_ud + s * (H_N * D_DIM)];
        const float kk  = dtv * uv;
        const int sbc = __builtin_amdgcn_readfirstlane(base_bc + s * (H_N * N_DIM));
        const float4* B4 = reinterpret_cast<const float4*>(Bp + sbc);
        float Br[N_DIM];
#pragma unroll
        for (int j = 0; j < 8; ++j) {
            float4 v = B4[j];
            Br[4*j+0] = v.x; Br[4*j+1] = v.y; Br[4*j+2] = v.z; Br[4*j+3] = v.w;
        }
#pragma unroll
        for (int n = 0; n < N_DIM; ++n) {
            const float e = __builtin_amdgcn_exp2f(dtv * Aneg[n]);
            aP[n] = aP[n] * e;
            bA[n] = fmaf(e, bA[n], kk * Br[n]);
        }
    }

    {
        const int aggbase = chunk * (64 * 1024) + ch;
#pragma unroll
        for (int n = 0; n < N_DIM; ++n) {
            agg[aggbase + n * 1024]        = aP[n];
            agg[aggbase + (32 + n) * 1024] = bA[n];
        }
    }

    cg::this_grid().sync();

    // ---------------- phase B: cross-chunk scan (32768 threads) ----------------
    {
        const int T = blockIdx.x * 512 + threadIdx.x;
        if (T < 32 * 1024) {
            const int sch = T & 1023;
            const int n   = T >> 10;
            const float* ap = agg + n * 1024 + sch;
            const float* bp = agg + (32 + n) * 1024 + sch;
            float*       pp = pref + n * 1024 + sch;
            float p = 0.0f;
            for (int k = 0; k < NC; k += 4) {
                const float a0 = ap[(size_t)(k + 0) * 65536], b0 = bp[(size_t)(k + 0) * 65536];
                const float a1 = ap[(size_t)(k + 1) * 65536], b1 = bp[(size_t)(k + 1) * 65536];
                const float a2 = ap[(size_t)(k + 2) * 65536], b2 = bp[(size_t)(k + 2) * 65536];
                const float a3 = ap[(size_t)(k + 3) * 65536], b3 = bp[(size_t)(k + 3) * 65536];
                pp[(size_t)(k + 0) * 32768] = p; p = fmaf(a0, p, b0);
                pp[(size_t)(k + 1) * 32768] = p; p = fmaf(a1, p, b1);
                pp[(size_t)(k + 2) * 32768] = p; p = fmaf(a2, p, b2);
                pp[(size_t)(k + 3) * 32768] = p; p = fmaf(a3, p, b3);
            }
        }
    }

    cg::this_grid().sync();

    // ---------------- phase C: rescan chunk with incoming prefix ----------------
    float h[N_DIM];
    {
        const int pbase = chunk * (32 * 1024) + ch;
#pragma unroll
        for (int n = 0; n < N_DIM; ++n) h[n] = pref[pbase + n * 1024];
    }

    const float Dv = Dp[hh];

#pragma unroll 2
    for (int t = 0; t < L_CH; ++t) {
        const int s = s0 + t;
        const float dtv = dtp[base_ud + s * (H_N * D_DIM)];
        const float uv  = up [base_ud + s * (H_N * D_DIM)];
        const float kk  = dtv * uv;
        const int sbc = __builtin_amdgcn_readfirstlane(base_bc + s * (H_N * N_DIM));
        const float4* B4 = reinterpret_cast<const float4*>(Bp + sbc);
        const float4* C4 = reinterpret_cast<const float4*>(Cp + sbc);
        float Br[N_DIM], Cr[N_DIM];
#pragma unroll
        for (int j = 0; j < 8; ++j) {
            float4 v = B4[j];
            Br[4*j+0] = v.x; Br[4*j+1] = v.y; Br[4*j+2] = v.z; Br[4*j+3] = v.w;
            float4 c = C4[j];
            Cr[4*j+0] = c.x; Cr[4*j+1] = c.y; Cr[4*j+2] = c.z; Cr[4*j+3] = c.w;
        }
        float y0 = 0.0f, y1 = 0.0f, y2 = 0.0f, y3 = 0.0f;
#pragma unroll
        for (int n = 0; n < N_DIM; ++n) {
            const float e = __builtin_amdgcn_exp2f(dtv * Aneg[n]);
            h[n] = fmaf(e, h[n], kk * Br[n]);
            if ((n & 3) == 0)      y0 = fmaf(h[n], Cr[n], y0);
            else if ((n & 3) == 1) y1 = fmaf(h[n], Cr[n], y1);
            else if ((n & 3) == 2) y2 = fmaf(h[n], Cr[n], y2);
            else                   y3 = fmaf(h[n], Cr[n], y3);
        }
        outp[base_ud + s * (H_N * D_DIM)] = fmaf(Dv, uv, (y0 + y1) + (y2 + y3));
    }
}

} // namespace

extern "C" void kernel_launch(void* const* d_in, const int* in_sizes, int n_in,
                              void* d_out, int out_size, void* d_ws, size_t ws_size,
                              hipStream_t stream)
{
    const float* u  = (const float*)d_in[0];
    const float* dt = (const float*)d_in[1];
    const float* A  = (const float*)d_in[2];
    const float* B  = (const float*)d_in[3];
    const float* C  = (const float*)d_in[4];
    const float* D  = (const float*)d_in[5];
    float* out = (float*)d_out;

    float* agg  = (float*)d_ws;                          // NC*64*1024 floats = 33.5 MB
    float* pref = agg + (size_t)NC * 64 * 1024;          // NC*32*1024 floats = 16.8 MB

    void* args[] = { (void*)&u, (void*)&dt, (void*)&A, (void*)&B, (void*)&C,
                     (void*)&D, (void*)&out, (void*)&agg, (void*)&pref };
    hipLaunchCooperativeKernel(reinterpret_cast<void*>(ssm_coop),
                               dim3(256), dim3(512), args, 0, stream);
}

// Round 6
// 102.113 us; speedup vs baseline: 12.3887x; 1.3934x over previous
//
#include <hip/hip_runtime.h>

namespace {

constexpr int S_LEN = 2048;
constexpr int H_N   = 8;
constexpr int D_DIM = 64;
constexpr int N_DIM = 32;
constexpr int WPB   = 8;              // waves per block
constexpr int TW    = 8;              // timesteps per wave
constexpr int SPB   = WPB * TW;       // 64 timesteps per block
constexpr int NCB   = S_LEN / SPB;    // 32 superchunks per (b,h)
constexpr float NLOG2E = -1.4426950408889634f;

// agg : [kb][slot 0..63][ch 0..1023]  slot n = aBlk[n], 32+n = bBlk[n]; kb stride 65536
// pref: [kb][n 0..31][ch 0..1023]     state entering superchunk kb;     kb stride 32768
// Block = bh*32 + kb ; wave w owns steps s0 = kb*64 + w*8 .. +7 ; lane = d.

__device__ __forceinline__ void load_f32x8(const float4* p, float* dst) {
#pragma unroll
    for (int j = 0; j < 8; ++j) {
        float4 v = p[j];
        dst[4*j+0] = v.x; dst[4*j+1] = v.y; dst[4*j+2] = v.z; dst[4*j+3] = v.w;
    }
}

__global__ __launch_bounds__(512, 4) void ssm_k1(
    const float* __restrict__ dtp, const float* __restrict__ up,
    const float* __restrict__ Ap,  const float* __restrict__ Bp,
    float* __restrict__ agg)
{
    __shared__ float2 buf[D_DIM * 33];

    const int w    = threadIdx.x >> 6;
    const int lane = threadIdx.x & 63;
    const int bh   = blockIdx.x >> 5;
    const int kb   = blockIdx.x & 31;
    const int b = bh >> 3, hh = bh & 7;
    const int d = lane;
    const int ch = bh * 64 + d;

    const float* Arow = Ap + (hh * D_DIM + d) * N_DIM;
    float Aneg[N_DIM];
#pragma unroll
    for (int n = 0; n < N_DIM; ++n) Aneg[n] = NLOG2E * Arow[n];

    const int base_ud = b * (S_LEN * H_N * D_DIM) + hh * D_DIM + d;
    const int base_bc = b * (S_LEN * H_N * N_DIM) + hh * N_DIM;
    const int s0 = kb * SPB + w * TW;

    float aP[N_DIM], bA[N_DIM];
#pragma unroll
    for (int n = 0; n < N_DIM; ++n) { aP[n] = 1.0f; bA[n] = 0.0f; }

#pragma unroll 4
    for (int t = 0; t < TW; ++t) {
        const int s = s0 + t;
        const float dtv = dtp[base_ud + s * (H_N * D_DIM)];
        const float uv  = up [base_ud + s * (H_N * D_DIM)];
        const float kk  = dtv * uv;
        const int sbc = __builtin_amdgcn_readfirstlane(base_bc + s * (H_N * N_DIM));
        float Br[N_DIM];
        load_f32x8(reinterpret_cast<const float4*>(Bp + sbc), Br);
#pragma unroll
        for (int n = 0; n < N_DIM; ++n) {
            const float e = __builtin_amdgcn_exp2f(dtv * Aneg[n]);
            aP[n] = aP[n] * e;
            bA[n] = fmaf(e, bA[n], kk * Br[n]);
        }
    }

    // in-block ripple: after this, (Pa,Pb) = exclusive prefix of waves 0..w-1
    float Pa[N_DIM], Pb[N_DIM];
#pragma unroll
    for (int n = 0; n < N_DIM; ++n) { Pa[n] = 1.0f; Pb[n] = 0.0f; }

    for (int stepw = 0; stepw < WPB; ++stepw) {
        if (w == stepw) {
            if (w > 0) {
#pragma unroll
                for (int n = 0; n < N_DIM; ++n) {
                    float2 g = buf[d * 33 + n];
                    Pa[n] = g.x; Pb[n] = g.y;
                }
            }
            if (w < WPB - 1) {
#pragma unroll
                for (int n = 0; n < N_DIM; ++n)
                    buf[d * 33 + n] = make_float2(aP[n] * Pa[n],
                                                  fmaf(aP[n], Pb[n], bA[n]));
            }
        }
        __syncthreads();
    }

    if (w == WPB - 1) {
        const int ab = kb * (64 * 1024) + ch;
#pragma unroll
        for (int n = 0; n < N_DIM; ++n) {
            agg[ab + n * 1024]        = aP[n] * Pa[n];
            agg[ab + (32 + n) * 1024] = fmaf(aP[n], Pb[n], bA[n]);
        }
    }
}

__global__ __launch_bounds__(256) void ssm_k2(
    const float* __restrict__ agg, float* __restrict__ pref)
{
    const int T  = blockIdx.x * 256 + threadIdx.x;   // 32768 threads = (n, ch)
    const int ch = T & 1023;
    const int n  = T >> 10;
    const float* ap = agg + n * 1024 + ch;
    const float* bp = agg + (32 + n) * 1024 + ch;
    float*       pp = pref + n * 1024 + ch;

    float p = 0.0f;
#pragma unroll
    for (int k = 0; k < NCB; k += 4) {
        const float a0 = ap[(k + 0) * 65536], b0 = bp[(k + 0) * 65536];
        const float a1 = ap[(k + 1) * 65536], b1 = bp[(k + 1) * 65536];
        const float a2 = ap[(k + 2) * 65536], b2 = bp[(k + 2) * 65536];
        const float a3 = ap[(k + 3) * 65536], b3 = bp[(k + 3) * 65536];
        pp[(k + 0) * 32768] = p; p = fmaf(a0, p, b0);
        pp[(k + 1) * 32768] = p; p = fmaf(a1, p, b1);
        pp[(k + 2) * 32768] = p; p = fmaf(a2, p, b2);
        pp[(k + 3) * 32768] = p; p = fmaf(a3, p, b3);
    }
}

__global__ __launch_bounds__(512, 2) void ssm_k3(
    const float* __restrict__ dtp, const float* __restrict__ up,
    const float* __restrict__ Ap,  const float* __restrict__ Bp,
    const float* __restrict__ Cp,  const float* __restrict__ Dp,
    const float* __restrict__ pref, float* __restrict__ outp)
{
    __shared__ float2 buf[D_DIM * 33];

    const int w    = threadIdx.x >> 6;
    const int lane = threadIdx.x & 63;
    const int bh   = blockIdx.x >> 5;
    const int kb   = blockIdx.x & 31;
    const int b = bh >> 3, hh = bh & 7;
    const int d = lane;
    const int ch = bh * 64 + d;

    const float* Arow = Ap + (hh * D_DIM + d) * N_DIM;
    float Aneg[N_DIM];
#pragma unroll
    for (int n = 0; n < N_DIM; ++n) Aneg[n] = NLOG2E * Arow[n];

    const int base_ud = b * (S_LEN * H_N * D_DIM) + hh * D_DIM + d;
    const int base_bc = b * (S_LEN * H_N * N_DIM) + hh * N_DIM;
    const int s0 = kb * SPB + w * TW;

    // ---- recompute my wave's 8-step transform ----
    float aP[N_DIM], bA[N_DIM];
#pragma unroll
    for (int n = 0; n < N_DIM; ++n) { aP[n] = 1.0f; bA[n] = 0.0f; }

#pragma unroll 4
    for (int t = 0; t < TW; ++t) {
        const int s = s0 + t;
        const float dtv = dtp[base_ud + s * (H_N * D_DIM)];
        const float uv  = up [base_ud + s * (H_N * D_DIM)];
        const float kk  = dtv * uv;
        const int sbc = __builtin_amdgcn_readfirstlane(base_bc + s * (H_N * N_DIM));
        float Br[N_DIM];
        load_f32x8(reinterpret_cast<const float4*>(Bp + sbc), Br);
#pragma unroll
        for (int n = 0; n < N_DIM; ++n) {
            const float e = __builtin_amdgcn_exp2f(dtv * Aneg[n]);
            aP[n] = aP[n] * e;
            bA[n] = fmaf(e, bA[n], kk * Br[n]);
        }
    }

    // ---- in-block ripple → exclusive wave prefix (Pa,Pb) ----
    float Pa[N_DIM], Pb[N_DIM];
#pragma unroll
    for (int n = 0; n < N_DIM; ++n) { Pa[n] = 1.0f; Pb[n] = 0.0f; }

    for (int stepw = 0; stepw < WPB; ++stepw) {
        if (w == stepw) {
            if (w > 0) {
#pragma unroll
                for (int n = 0; n < N_DIM; ++n) {
                    float2 g = buf[d * 33 + n];
                    Pa[n] = g.x; Pb[n] = g.y;
                }
            }
            if (w < WPB - 1) {
#pragma unroll
                for (int n = 0; n < N_DIM; ++n)
                    buf[d * 33 + n] = make_float2(aP[n] * Pa[n],
                                                  fmaf(aP[n], Pb[n], bA[n]));
            }
        }
        __syncthreads();
    }

    // ---- compose with block-entry state ----
    float h[N_DIM];
    {
        const int pb = kb * (32 * 1024) + ch;
#pragma unroll
        for (int n = 0; n < N_DIM; ++n)
            h[n] = fmaf(Pa[n], pref[pb + n * 1024], Pb[n]);
    }

    // ---- rescan 8 steps, emit y ----
    const float Dv = Dp[hh];

#pragma unroll 2
    for (int t = 0; t < TW; ++t) {
        const int s = s0 + t;
        const float dtv = dtp[base_ud + s * (H_N * D_DIM)];
        const float uv  = up [base_ud + s * (H_N * D_DIM)];
        const float kk  = dtv * uv;
        const int sbc = __builtin_amdgcn_readfirstlane(base_bc + s * (H_N * N_DIM));
        float Br[N_DIM], Cr[N_DIM];
        load_f32x8(reinterpret_cast<const float4*>(Bp + sbc), Br);
        load_f32x8(reinterpret_cast<const float4*>(Cp + sbc), Cr);
        float y0 = 0.0f, y1 = 0.0f, y2 = 0.0f, y3 = 0.0f;
#pragma unroll
        for (int n = 0; n < N_DIM; ++n) {
            const float e = __builtin_amdgcn_exp2f(dtv * Aneg[n]);
            h[n] = fmaf(e, h[n], kk * Br[n]);
            if ((n & 3) == 0)      y0 = fmaf(h[n], Cr[n], y0);
            else if ((n & 3) == 1) y1 = fmaf(h[n], Cr[n], y1);
            else if ((n & 3) == 2) y2 = fmaf(h[n], Cr[n], y2);
            else                   y3 = fmaf(h[n], Cr[n], y3);
        }
        outp[base_ud + s * (H_N * D_DIM)] = fmaf(Dv, uv, (y0 + y1) + (y2 + y3));
    }
}

} // namespace

extern "C" void kernel_launch(void* const* d_in, const int* in_sizes, int n_in,
                              void* d_out, int out_size, void* d_ws, size_t ws_size,
                              hipStream_t stream)
{
    const float* u  = (const float*)d_in[0];
    const float* dt = (const float*)d_in[1];
    const float* A  = (const float*)d_in[2];
    const float* B  = (const float*)d_in[3];
    const float* C  = (const float*)d_in[4];
    const float* D  = (const float*)d_in[5];
    float* out = (float*)d_out;

    float* agg  = (float*)d_ws;                        // 32*64*1024 floats = 8.4 MB
    float* pref = agg + (size_t)NCB * 64 * 1024;       // 32*32*1024 floats = 4.2 MB

    ssm_k1<<<dim3(16 * NCB), dim3(512), 0, stream>>>(dt, u, A, B, agg);
    ssm_k2<<<dim3(128),      dim3(256), 0, stream>>>(agg, pref);
    ssm_k3<<<dim3(16 * NCB), dim3(512), 0, stream>>>(dt, u, A, B, C, D, pref, out);
}

// Round 7
// 86.211 us; speedup vs baseline: 14.6739x; 1.1845x over previous
//
#include <hip/hip_runtime.h>

namespace {

constexpr int S_LEN = 2048;
constexpr int H_N   = 8;
constexpr int D_DIM = 64;
constexpr int N_DIM = 32;
constexpr int WPB   = 8;              // waves per block
constexpr int TW    = 8;              // timesteps per wave
constexpr int SPB   = WPB * TW;       // 64 timesteps per block
constexpr int NCB   = S_LEN / SPB;    // 32 superchunks per (b,h)
constexpr float NLOG2E = -1.4426950408889634f;

// agg : [kb][slot 0..63][ch 0..1023]  slot n = aBlk[n], 32+n = bBlk[n]; kb stride 65536
// pref: [kb][n 0..31][ch 0..1023]     state entering superchunk kb;     kb stride 32768
// Block = bh*32 + kb ; wave w owns steps tt = w*8 .. w*8+7 of the 64-step slab; lane = d.

__global__ __launch_bounds__(512, 2) void ssm_k1(
    const float* __restrict__ dtp, const float* __restrict__ up,
    const float* __restrict__ Ap,  const float* __restrict__ Bp,
    float* __restrict__ agg)
{
    __shared__ float ldt[SPB * 64];       // [t][d] 16 KB
    __shared__ float lu [SPB * 64];       // 16 KB
    __shared__ float lB [SPB * 32];       // [t][n]  8 KB
    __shared__ float bufA[D_DIM * 33];    // ripple, padded (2-way only)
    __shared__ float bufB[D_DIM * 33];

    const int tid  = threadIdx.x;
    const int w    = tid >> 6;
    const int lane = tid & 63;
    const int bh   = blockIdx.x >> 5;
    const int kb   = blockIdx.x & 31;
    const int b = bh >> 3, hh = bh & 7;
    const int d = lane;
    const int ch = bh * 64 + d;

    const int udbase = b * (S_LEN * 512) + kb * (SPB * 512) + hh * 64;
    const int bcbase = b * (S_LEN * 256) + kb * (SPB * 256) + hh * 32;

    // ---- stage slabs (coalesced float4) ----
    {
        int r = tid >> 4, c = tid & 15;
#pragma unroll
        for (int it = 0; it < 2; ++it, r += 32) {
            *(float4*)&ldt[r * 64 + c * 4] = *(const float4*)(dtp + udbase + r * 512 + c * 4);
            *(float4*)&lu [r * 64 + c * 4] = *(const float4*)(up  + udbase + r * 512 + c * 4);
        }
        const int rb = tid >> 3, cb = tid & 7;
        *(float4*)&lB[rb * 32 + cb * 4] = *(const float4*)(Bp + bcbase + rb * 256 + cb * 4);
    }

    const float* Arow = Ap + (hh * D_DIM + d) * N_DIM;
    float Aneg[N_DIM];
#pragma unroll
    for (int n = 0; n < N_DIM; ++n) Aneg[n] = NLOG2E * Arow[n];

    __syncthreads();

    // ---- pass A: 8-step transform from LDS ----
    float aP[N_DIM], bA[N_DIM];
#pragma unroll
    for (int n = 0; n < N_DIM; ++n) { aP[n] = 1.0f; bA[n] = 0.0f; }

#pragma unroll 2
    for (int t = 0; t < TW; ++t) {
        const int tt = w * TW + t;
        const float dtv = ldt[tt * 64 + d];
        const float uv  = lu [tt * 64 + d];
        const float kk  = dtv * uv;
#pragma unroll
        for (int j = 0; j < 8; ++j) {
            const float4 Bv = *(const float4*)&lB[tt * 32 + j * 4];
#pragma unroll
            for (int q = 0; q < 4; ++q) {
                const int n = j * 4 + q;
                const float bq = (q == 0) ? Bv.x : (q == 1) ? Bv.y : (q == 2) ? Bv.z : Bv.w;
                const float e = __builtin_amdgcn_exp2f(dtv * Aneg[n]);
                aP[n] = aP[n] * e;
                bA[n] = fmaf(e, bA[n], kk * bq);
            }
        }
    }

    // ---- serial ripple, stream-composed; wave 7 writes block aggregate ----
    for (int sw = 0; sw < WPB; ++sw) {
        if (w == sw) {
            if (w == 0) {
#pragma unroll
                for (int n = 0; n < N_DIM; ++n) {
                    bufA[d * 33 + n] = aP[n];
                    bufB[d * 33 + n] = bA[n];
                }
            } else if (w < WPB - 1) {
#pragma unroll
                for (int n = 0; n < N_DIM; ++n) {
                    const float gA = bufA[d * 33 + n];
                    const float gB = bufB[d * 33 + n];
                    bufA[d * 33 + n] = aP[n] * gA;
                    bufB[d * 33 + n] = fmaf(aP[n], gB, bA[n]);
                }
            } else {
                const int ab = kb * 65536 + ch;
#pragma unroll
                for (int n = 0; n < N_DIM; ++n) {
                    const float gA = bufA[d * 33 + n];
                    const float gB = bufB[d * 33 + n];
                    agg[ab + n * 1024]        = aP[n] * gA;
                    agg[ab + (32 + n) * 1024] = fmaf(aP[n], gB, bA[n]);
                }
            }
        }
        if (sw < WPB - 1) __syncthreads();
    }
}

__global__ __launch_bounds__(256) void ssm_k2(
    const float* __restrict__ agg, float* __restrict__ pref)
{
    const int T  = blockIdx.x * 256 + threadIdx.x;   // 32768 threads = (n, ch)
    const int ch = T & 1023;
    const int n  = T >> 10;
    const float* ap = agg + n * 1024 + ch;
    const float* bp = agg + (32 + n) * 1024 + ch;
    float*       pp = pref + n * 1024 + ch;

    float p = 0.0f;
#pragma unroll
    for (int k = 0; k < NCB; k += 4) {
        const float a0 = ap[(k + 0) * 65536], b0 = bp[(k + 0) * 65536];
        const float a1 = ap[(k + 1) * 65536], b1 = bp[(k + 1) * 65536];
        const float a2 = ap[(k + 2) * 65536], b2 = bp[(k + 2) * 65536];
        const float a3 = ap[(k + 3) * 65536], b3 = bp[(k + 3) * 65536];
        pp[(k + 0) * 32768] = p; p = fmaf(a0, p, b0);
        pp[(k + 1) * 32768] = p; p = fmaf(a1, p, b1);
        pp[(k + 2) * 32768] = p; p = fmaf(a2, p, b2);
        pp[(k + 3) * 32768] = p; p = fmaf(a3, p, b3);
    }
}

__global__ __launch_bounds__(512, 2) void ssm_k3(
    const float* __restrict__ dtp, const float* __restrict__ up,
    const float* __restrict__ Ap,  const float* __restrict__ Bp,
    const float* __restrict__ Cp,  const float* __restrict__ Dp,
    const float* __restrict__ pref, float* __restrict__ outp)
{
    __shared__ float ldt[SPB * 64];
    __shared__ float lu [SPB * 64];
    __shared__ float lB [SPB * 32];
    __shared__ float lC [SPB * 32];
    __shared__ float bufA[D_DIM * 33];
    __shared__ float bufB[D_DIM * 33];

    const int tid  = threadIdx.x;
    const int w    = tid >> 6;
    const int lane = tid & 63;
    const int bh   = blockIdx.x >> 5;
    const int kb   = blockIdx.x & 31;
    const int b = bh >> 3, hh = bh & 7;
    const int d = lane;
    const int ch = bh * 64 + d;

    const int udbase = b * (S_LEN * 512) + kb * (SPB * 512) + hh * 64;
    const int bcbase = b * (S_LEN * 256) + kb * (SPB * 256) + hh * 32;

    {
        int r = tid >> 4, c = tid & 15;
#pragma unroll
        for (int it = 0; it < 2; ++it, r += 32) {
            *(float4*)&ldt[r * 64 + c * 4] = *(const float4*)(dtp + udbase + r * 512 + c * 4);
            *(float4*)&lu [r * 64 + c * 4] = *(const float4*)(up  + udbase + r * 512 + c * 4);
        }
        const int rb = tid >> 3, cb = tid & 7;
        *(float4*)&lB[rb * 32 + cb * 4] = *(const float4*)(Bp + bcbase + rb * 256 + cb * 4);
        *(float4*)&lC[rb * 32 + cb * 4] = *(const float4*)(Cp + bcbase + rb * 256 + cb * 4);
    }

    const float* Arow = Ap + (hh * D_DIM + d) * N_DIM;
    float Aneg[N_DIM];
#pragma unroll
    for (int n = 0; n < N_DIM; ++n) Aneg[n] = NLOG2E * Arow[n];

    __syncthreads();

    // ---- pass A: recompute 8-step transform from LDS ----
    float aP[N_DIM], bA[N_DIM];
#pragma unroll
    for (int n = 0; n < N_DIM; ++n) { aP[n] = 1.0f; bA[n] = 0.0f; }

#pragma unroll 2
    for (int t = 0; t < TW; ++t) {
        const int tt = w * TW + t;
        const float dtv = ldt[tt * 64 + d];
        const float uv  = lu [tt * 64 + d];
        const float kk  = dtv * uv;
#pragma unroll
        for (int j = 0; j < 8; ++j) {
            const float4 Bv = *(const float4*)&lB[tt * 32 + j * 4];
#pragma unroll
            for (int q = 0; q < 4; ++q) {
                const int n = j * 4 + q;
                const float bq = (q == 0) ? Bv.x : (q == 1) ? Bv.y : (q == 2) ? Bv.z : Bv.w;
                const float e = __builtin_amdgcn_exp2f(dtv * Aneg[n]);
                aP[n] = aP[n] * e;
                bA[n] = fmaf(e, bA[n], kk * bq);
            }
        }
    }

    // ---- ripple; each wave composes its entering state h from pref + prefix ----
    float h[N_DIM];
    const int pb = kb * 32768 + ch;

    for (int sw = 0; sw < WPB; ++sw) {
        if (w == sw) {
            if (w == 0) {
#pragma unroll
                for (int n = 0; n < N_DIM; ++n) {
                    h[n] = pref[pb + n * 1024];
                    bufA[d * 33 + n] = aP[n];
                    bufB[d * 33 + n] = bA[n];
                }
            } else {
#pragma unroll
                for (int n = 0; n < N_DIM; ++n) {
                    const float gA = bufA[d * 33 + n];
                    const float gB = bufB[d * 33 + n];
                    h[n] = fmaf(gA, pref[pb + n * 1024], gB);
                    if (w < WPB - 1) {
                        bufA[d * 33 + n] = aP[n] * gA;
                        bufB[d * 33 + n] = fmaf(aP[n], gB, bA[n]);
                    }
                }
            }
        }
        if (sw < WPB - 1) __syncthreads();
    }

    // ---- pass C: rescan 8 steps from LDS, emit y ----
    const float Dv = Dp[hh];

#pragma unroll 2
    for (int t = 0; t < TW; ++t) {
        const int tt = w * TW + t;
        const float dtv = ldt[tt * 64 + d];
        const float uv  = lu [tt * 64 + d];
        const float kk  = dtv * uv;
        float y0 = 0.0f, y1 = 0.0f, y2 = 0.0f, y3 = 0.0f;
#pragma unroll
        for (int j = 0; j < 8; ++j) {
            const float4 Bv = *(const float4*)&lB[tt * 32 + j * 4];
            const float4 Cv = *(const float4*)&lC[tt * 32 + j * 4];
#pragma unroll
            for (int q = 0; q < 4; ++q) {
                const int n = j * 4 + q;
                const float bq = (q == 0) ? Bv.x : (q == 1) ? Bv.y : (q == 2) ? Bv.z : Bv.w;
                const float cq = (q == 0) ? Cv.x : (q == 1) ? Cv.y : (q == 2) ? Cv.z : Cv.w;
                const float e = __builtin_amdgcn_exp2f(dtv * Aneg[n]);
                h[n] = fmaf(e, h[n], kk * bq);
                if (q == 0)      y0 = fmaf(h[n], cq, y0);
                else if (q == 1) y1 = fmaf(h[n], cq, y1);
                else if (q == 2) y2 = fmaf(h[n], cq, y2);
                else             y3 = fmaf(h[n], cq, y3);
            }
        }
        outp[udbase + tt * 512 + d] = fmaf(Dv, uv, (y0 + y1) + (y2 + y3));
    }
}

} // namespace

extern "C" void kernel_launch(void* const* d_in, const int* in_sizes, int n_in,
                              void* d_out, int out_size, void* d_ws, size_t ws_size,
                              hipStream_t stream)
{
    const float* u  = (const float*)d_in[0];
    const float* dt = (const float*)d_in[1];
    const float* A  = (const float*)d_in[2];
    const float* B  = (const float*)d_in[3];
    const float* C  = (const float*)d_in[4];
    const float* D  = (const float*)d_in[5];
    float* out = (float*)d_out;

    float* agg  = (float*)d_ws;                        // 32*64*1024 floats = 8.4 MB
    float* pref = agg + (size_t)NCB * 64 * 1024;       // 32*32*1024 floats = 4.2 MB

    ssm_k1<<<dim3(16 * NCB), dim3(512), 0, stream>>>(dt, u, A, B, agg);
    ssm_k2<<<dim3(128),      dim3(256), 0, stream>>>(agg, pref);
    ssm_k3<<<dim3(16 * NCB), dim3(512), 0, stream>>>(dt, u, A, B, C, D, pref, out);
}

// Round 8
// 53.368 us; speedup vs baseline: 23.7042x; 1.6154x over previous
//
#include <hip/hip_runtime.h>

namespace {

constexpr int S_LEN = 2048;
constexpr int H_N   = 8;
constexpr int D_DIM = 64;
constexpr int N_DIM = 32;
constexpr int TW    = 16;             // timesteps per wave-pair
constexpr int SPB   = 64;             // timesteps per block
constexpr int NCB   = S_LEN / SPB;    // 32 superchunks per (b,h)
constexpr float NLOG2E = -1.4426950408889634f;

// agg : [kb][slot 0..63][ch 0..1023]  slot n = aBlk[n], 32+n = bBlk[n]; kb stride 65536
// pref: [kb][n 0..31][ch 0..1023]     state entering superchunk kb;     kb stride 32768
// Block = bh*32 + kb. Wave w: tw = w>>1 (time turn), dh = w&1 (d-half).
// Lane: dlow = lane&31, nh = lane>>5 ; d = dh*32+dlow ; thread owns n in [nh*16, nh*16+16).

__global__ __launch_bounds__(512, 2) void ssm_k1(
    const float* __restrict__ dtp, const float* __restrict__ up,
    const float* __restrict__ Ap,  const float* __restrict__ Bp,
    float* __restrict__ agg)
{
    __shared__ float ldt[SPB * 64];       // [t][d] 16 KB
    __shared__ float lu [SPB * 64];       // 16 KB
    __shared__ float lB [SPB * 32];       // [t][n]  8 KB
    __shared__ float bufA[D_DIM * 33];    // ripple (2-way bank alias only)
    __shared__ float bufB[D_DIM * 33];

    const int tid  = threadIdx.x;
    const int w    = tid >> 6;
    const int lane = tid & 63;
    const int tw   = w >> 1;
    const int dh   = w & 1;
    const int dlow = lane & 31;
    const int nh   = lane >> 5;
    const int bh   = blockIdx.x >> 5;
    const int kb   = blockIdx.x & 31;
    const int b = bh >> 3, hh = bh & 7;
    const int d  = dh * 32 + dlow;
    const int n0 = nh * 16;
    const int ch = bh * 64 + d;

    const int udbase = b * (S_LEN * 512) + kb * (SPB * 512) + hh * 64;
    const int bcbase = b * (S_LEN * 256) + kb * (SPB * 256) + hh * 32;

    // ---- stage slabs (coalesced float4) ----
    {
        int r = tid >> 4, c = tid & 15;
#pragma unroll
        for (int it = 0; it < 2; ++it, r += 32) {
            *(float4*)&ldt[r * 64 + c * 4] = *(const float4*)(dtp + udbase + r * 512 + c * 4);
            *(float4*)&lu [r * 64 + c * 4] = *(const float4*)(up  + udbase + r * 512 + c * 4);
        }
        const int rb = tid >> 3, cb = tid & 7;
        *(float4*)&lB[rb * 32 + cb * 4] = *(const float4*)(Bp + bcbase + rb * 256 + cb * 4);
    }

    float Aneg[16];
    {
        const float* Arow = Ap + (hh * D_DIM + d) * N_DIM + n0;
#pragma unroll
        for (int j = 0; j < 4; ++j) {
            float4 a4 = *(const float4*)(Arow + j * 4);
            Aneg[4*j+0] = NLOG2E * a4.x; Aneg[4*j+1] = NLOG2E * a4.y;
            Aneg[4*j+2] = NLOG2E * a4.z; Aneg[4*j+3] = NLOG2E * a4.w;
        }
    }

    __syncthreads();

    // ---- pass A: 16-step transform from LDS ----
    float aP[16], bA[16];
#pragma unroll
    for (int j = 0; j < 16; ++j) { aP[j] = 1.0f; bA[j] = 0.0f; }

#pragma unroll 2
    for (int t = 0; t < TW; ++t) {
        const int tt = tw * TW + t;
        const float dtv = ldt[tt * 64 + d];
        const float uv  = lu [tt * 64 + d];
        const float kk  = dtv * uv;
#pragma unroll
        for (int j = 0; j < 4; ++j) {
            const float4 Bv = *(const float4*)&lB[tt * 32 + n0 + j * 4];
#pragma unroll
            for (int q = 0; q < 4; ++q) {
                const int jn = j * 4 + q;
                const float bq = (q == 0) ? Bv.x : (q == 1) ? Bv.y : (q == 2) ? Bv.z : Bv.w;
                const float e = __builtin_amdgcn_exp2f(dtv * Aneg[jn]);
                aP[jn] = aP[jn] * e;
                bA[jn] = fmaf(e, bA[jn], kk * bq);
            }
        }
    }

    // ---- 4-turn ripple; turn 3 writes block aggregate ----
    for (int stw = 0; stw < 4; ++stw) {
        if (tw == stw) {
            if (tw == 0) {
#pragma unroll
                for (int j = 0; j < 16; ++j) {
                    bufA[d * 33 + n0 + j] = aP[j];
                    bufB[d * 33 + n0 + j] = bA[j];
                }
            } else if (tw < 3) {
#pragma unroll
                for (int j = 0; j < 16; ++j) {
                    const float gA = bufA[d * 33 + n0 + j];
                    const float gB = bufB[d * 33 + n0 + j];
                    bufA[d * 33 + n0 + j] = aP[j] * gA;
                    bufB[d * 33 + n0 + j] = fmaf(aP[j], gB, bA[j]);
                }
            } else {
                const int ab = kb * 65536 + ch;
#pragma unroll
                for (int j = 0; j < 16; ++j) {
                    const float gA = bufA[d * 33 + n0 + j];
                    const float gB = bufB[d * 33 + n0 + j];
                    agg[ab + (n0 + j) * 1024]        = aP[j] * gA;
                    agg[ab + (32 + n0 + j) * 1024]   = fmaf(aP[j], gB, bA[j]);
                }
            }
        }
        if (stw < 3) __syncthreads();
    }
}

__global__ __launch_bounds__(256) void ssm_k2(
    const float* __restrict__ agg, float* __restrict__ pref)
{
    const int T  = blockIdx.x * 256 + threadIdx.x;   // 32768 threads = (n, ch)
    const int ch = T & 1023;
    const int n  = T >> 10;
    const float* ap = agg + n * 1024 + ch;
    const float* bp = agg + (32 + n) * 1024 + ch;
    float*       pp = pref + n * 1024 + ch;

    float p = 0.0f;
#pragma unroll
    for (int k = 0; k < NCB; k += 4) {
        const float a0 = ap[(k + 0) * 65536], b0 = bp[(k + 0) * 65536];
        const float a1 = ap[(k + 1) * 65536], b1 = bp[(k + 1) * 65536];
        const float a2 = ap[(k + 2) * 65536], b2 = bp[(k + 2) * 65536];
        const float a3 = ap[(k + 3) * 65536], b3 = bp[(k + 3) * 65536];
        pp[(k + 0) * 32768] = p; p = fmaf(a0, p, b0);
        pp[(k + 1) * 32768] = p; p = fmaf(a1, p, b1);
        pp[(k + 2) * 32768] = p; p = fmaf(a2, p, b2);
        pp[(k + 3) * 32768] = p; p = fmaf(a3, p, b3);
    }
}

__global__ __launch_bounds__(512, 2) void ssm_k3(
    const float* __restrict__ dtp, const float* __restrict__ up,
    const float* __restrict__ Ap,  const float* __restrict__ Bp,
    const float* __restrict__ Cp,  const float* __restrict__ Dp,
    const float* __restrict__ pref, float* __restrict__ outp)
{
    __shared__ float ldt[SPB * 64];
    __shared__ float lu [SPB * 64];
    __shared__ float lB [SPB * 32];
    __shared__ float lC [SPB * 32];
    __shared__ float bufA[D_DIM * 33];
    __shared__ float bufB[D_DIM * 33];

    const int tid  = threadIdx.x;
    const int w    = tid >> 6;
    const int lane = tid & 63;
    const int tw   = w >> 1;
    const int dh   = w & 1;
    const int dlow = lane & 31;
    const int nh   = lane >> 5;
    const int bh   = blockIdx.x >> 5;
    const int kb   = blockIdx.x & 31;
    const int b = bh >> 3, hh = bh & 7;
    const int d  = dh * 32 + dlow;
    const int n0 = nh * 16;
    const int ch = bh * 64 + d;

    const int udbase = b * (S_LEN * 512) + kb * (SPB * 512) + hh * 64;
    const int bcbase = b * (S_LEN * 256) + kb * (SPB * 256) + hh * 32;

    {
        int r = tid >> 4, c = tid & 15;
#pragma unroll
        for (int it = 0; it < 2; ++it, r += 32) {
            *(float4*)&ldt[r * 64 + c * 4] = *(const float4*)(dtp + udbase + r * 512 + c * 4);
            *(float4*)&lu [r * 64 + c * 4] = *(const float4*)(up  + udbase + r * 512 + c * 4);
        }
        const int rb = tid >> 3, cb = tid & 7;
        *(float4*)&lB[rb * 32 + cb * 4] = *(const float4*)(Bp + bcbase + rb * 256 + cb * 4);
        *(float4*)&lC[rb * 32 + cb * 4] = *(const float4*)(Cp + bcbase + rb * 256 + cb * 4);
    }

    float Aneg[16];
    {
        const float* Arow = Ap + (hh * D_DIM + d) * N_DIM + n0;
#pragma unroll
        for (int j = 0; j < 4; ++j) {
            float4 a4 = *(const float4*)(Arow + j * 4);
            Aneg[4*j+0] = NLOG2E * a4.x; Aneg[4*j+1] = NLOG2E * a4.y;
            Aneg[4*j+2] = NLOG2E * a4.z; Aneg[4*j+3] = NLOG2E * a4.w;
        }
    }

    // hoisted block-entry state (latency overlaps pass A)
    float prefv[16];
    {
        const int pb = kb * 32768 + ch;
#pragma unroll
        for (int j = 0; j < 16; ++j) prefv[j] = pref[pb + (n0 + j) * 1024];
    }

    __syncthreads();

    // ---- pass A: recompute 16-step transform from LDS ----
    float aP[16], bA[16];
#pragma unroll
    for (int j = 0; j < 16; ++j) { aP[j] = 1.0f; bA[j] = 0.0f; }

#pragma unroll 2
    for (int t = 0; t < TW; ++t) {
        const int tt = tw * TW + t;
        const float dtv = ldt[tt * 64 + d];
        const float uv  = lu [tt * 64 + d];
        const float kk  = dtv * uv;
#pragma unroll
        for (int j = 0; j < 4; ++j) {
            const float4 Bv = *(const float4*)&lB[tt * 32 + n0 + j * 4];
#pragma unroll
            for (int q = 0; q < 4; ++q) {
                const int jn = j * 4 + q;
                const float bq = (q == 0) ? Bv.x : (q == 1) ? Bv.y : (q == 2) ? Bv.z : Bv.w;
                const float e = __builtin_amdgcn_exp2f(dtv * Aneg[jn]);
                aP[jn] = aP[jn] * e;
                bA[jn] = fmaf(e, bA[jn], kk * bq);
            }
        }
    }

    // ---- 4-turn ripple; wave composes its entering state h ----
    float h[16];
    for (int stw = 0; stw < 4; ++stw) {
        if (tw == stw) {
            if (tw == 0) {
#pragma unroll
                for (int j = 0; j < 16; ++j) {
                    h[j] = prefv[j];
                    bufA[d * 33 + n0 + j] = aP[j];
                    bufB[d * 33 + n0 + j] = bA[j];
                }
            } else {
#pragma unroll
                for (int j = 0; j < 16; ++j) {
                    const float gA = bufA[d * 33 + n0 + j];
                    const float gB = bufB[d * 33 + n0 + j];
                    h[j] = fmaf(gA, prefv[j], gB);
                    if (tw < 3) {
                        bufA[d * 33 + n0 + j] = aP[j] * gA;
                        bufB[d * 33 + n0 + j] = fmaf(aP[j], gB, bA[j]);
                    }
                }
            }
        }
        if (stw < 3) __syncthreads();
    }

    // ---- pass C: rescan 16 steps from LDS, combine n-halves, emit y ----
    const float Dv = Dp[hh];

#pragma unroll 2
    for (int t = 0; t < TW; ++t) {
        const int tt = tw * TW + t;
        const float dtv = ldt[tt * 64 + d];
        const float uv  = lu [tt * 64 + d];
        const float kk  = dtv * uv;
        float y0 = 0.0f, y1 = 0.0f, y2 = 0.0f, y3 = 0.0f;
#pragma unroll
        for (int j = 0; j < 4; ++j) {
            const float4 Bv = *(const float4*)&lB[tt * 32 + n0 + j * 4];
            const float4 Cv = *(const float4*)&lC[tt * 32 + n0 + j * 4];
#pragma unroll
            for (int q = 0; q < 4; ++q) {
                const int jn = j * 4 + q;
                const float bq = (q == 0) ? Bv.x : (q == 1) ? Bv.y : (q == 2) ? Bv.z : Bv.w;
                const float cq = (q == 0) ? Cv.x : (q == 1) ? Cv.y : (q == 2) ? Cv.z : Cv.w;
                const float e = __builtin_amdgcn_exp2f(dtv * Aneg[jn]);
                h[jn] = fmaf(e, h[jn], kk * bq);
                if (q == 0)      y0 = fmaf(h[jn], cq, y0);
                else if (q == 1) y1 = fmaf(h[jn], cq, y1);
                else if (q == 2) y2 = fmaf(h[jn], cq, y2);
                else             y3 = fmaf(h[jn], cq, y3);
            }
        }
        float y = (y0 + y1) + (y2 + y3);
        y += __shfl_xor(y, 32);
        if (nh == 0) outp[udbase + tt * 512 + d] = fmaf(Dv, uv, y);
    }
}

} // namespace

extern "C" void kernel_launch(void* const* d_in, const int* in_sizes, int n_in,
                              void* d_out, int out_size, void* d_ws, size_t ws_size,
                              hipStream_t stream)
{
    const float* u  = (const float*)d_in[0];
    const float* dt = (const float*)d_in[1];
    const float* A  = (const float*)d_in[2];
    const float* B  = (const float*)d_in[3];
    const float* C  = (const float*)d_in[4];
    const float* D  = (const float*)d_in[5];
    float* out = (float*)d_out;

    float* agg  = (float*)d_ws;                        // 32*64*1024 floats = 8.4 MB
    float* pref = agg + (size_t)NCB * 64 * 1024;       // 32*32*1024 floats = 4.2 MB

    ssm_k1<<<dim3(16 * NCB), dim3(512), 0, stream>>>(dt, u, A, B, agg);
    ssm_k2<<<dim3(128),      dim3(256), 0, stream>>>(agg, pref);
    ssm_k3<<<dim3(16 * NCB), dim3(512), 0, stream>>>(dt, u, A, B, C, D, pref, out);
}

// Round 9
// 49.406 us; speedup vs baseline: 25.6052x; 1.0802x over previous
//
#include <hip/hip_runtime.h>

namespace {

constexpr int S_LEN = 2048;
constexpr int H_N   = 8;
constexpr int D_DIM = 64;
constexpr int N_DIM = 32;
constexpr int TW    = 16;             // timesteps per wave-pair = chunk length
constexpr int SPB   = 64;             // timesteps per block slab
constexpr int NKB   = S_LEN / SPB;    // 32 slabs per (b,h)
constexpr int NKC   = S_LEN / TW;     // 128 chunks per (b,h)
constexpr float NLOG2E = -1.4426950408889634f;

// agg : [kc 0..127][slot 0..63][ch 0..1023]  slot n = aChunk[n], 32+n = bChunk[n]; kc stride 65536
// pref: [kc][n 0..31][ch 0..1023]            state entering chunk kc;              kc stride 32768
// Block = bh*32 + kb (64-step slab). Wave w: tw = w>>1 (chunk-in-slab), dh = w&1 (d-half).
// Lane: dlow = lane&31, nh = lane>>5 ; d = dh*32+dlow ; thread owns n in [nh*16, nh*16+16).
// Chunk id kc = kb*4 + tw.

__global__ __launch_bounds__(512, 2) void ssm_k1(
    const float* __restrict__ dtp, const float* __restrict__ up,
    const float* __restrict__ Ap,  const float* __restrict__ Bp,
    float* __restrict__ agg)
{
    __shared__ float ldt[SPB * 64];       // [t][d] 16 KB
    __shared__ float lu [SPB * 64];       // 16 KB
    __shared__ float lB [SPB * 32];       // [t][n]  8 KB

    const int tid  = threadIdx.x;
    const int w    = tid >> 6;
    const int lane = tid & 63;
    const int tw   = w >> 1;
    const int dh   = w & 1;
    const int dlow = lane & 31;
    const int nh   = lane >> 5;
    const int bh   = blockIdx.x >> 5;
    const int kb   = blockIdx.x & 31;
    const int b = bh >> 3, hh = bh & 7;
    const int d  = dh * 32 + dlow;
    const int n0 = nh * 16;
    const int ch = bh * 64 + d;

    const int udbase = b * (S_LEN * 512) + kb * (SPB * 512) + hh * 64;
    const int bcbase = b * (S_LEN * 256) + kb * (SPB * 256) + hh * 32;

    // ---- stage slabs (coalesced float4) ----
    {
        int r = tid >> 4, c = tid & 15;
#pragma unroll
        for (int it = 0; it < 2; ++it, r += 32) {
            *(float4*)&ldt[r * 64 + c * 4] = *(const float4*)(dtp + udbase + r * 512 + c * 4);
            *(float4*)&lu [r * 64 + c * 4] = *(const float4*)(up  + udbase + r * 512 + c * 4);
        }
        const int rb = tid >> 3, cb = tid & 7;
        *(float4*)&lB[rb * 32 + cb * 4] = *(const float4*)(Bp + bcbase + rb * 256 + cb * 4);
    }

    float Aneg[16];
    {
        const float* Arow = Ap + (hh * D_DIM + d) * N_DIM + n0;
#pragma unroll
        for (int j = 0; j < 4; ++j) {
            float4 a4 = *(const float4*)(Arow + j * 4);
            Aneg[4*j+0] = NLOG2E * a4.x; Aneg[4*j+1] = NLOG2E * a4.y;
            Aneg[4*j+2] = NLOG2E * a4.z; Aneg[4*j+3] = NLOG2E * a4.w;
        }
    }

    __syncthreads();

    // ---- pass A: 16-step chunk transform; aP via log-domain (sum of dt) ----
    float bA[16];
#pragma unroll
    for (int j = 0; j < 16; ++j) bA[j] = 0.0f;
    float sdt = 0.0f;

#pragma unroll 2
    for (int t = 0; t < TW; ++t) {
        const int tt = tw * TW + t;
        const float dtv = ldt[tt * 64 + d];
        const float uv  = lu [tt * 64 + d];
        const float kk  = dtv * uv;
        sdt += dtv;
#pragma unroll
        for (int j = 0; j < 4; ++j) {
            const float4 Bv = *(const float4*)&lB[tt * 32 + n0 + j * 4];
#pragma unroll
            for (int q = 0; q < 4; ++q) {
                const int jn = j * 4 + q;
                const float bq = (q == 0) ? Bv.x : (q == 1) ? Bv.y : (q == 2) ? Bv.z : Bv.w;
                const float e = __builtin_amdgcn_exp2f(dtv * Aneg[jn]);
                bA[jn] = fmaf(e, bA[jn], kk * bq);
            }
        }
    }

    // ---- store chunk (a, b) directly at chunk granularity ----
    const int kc = kb * 4 + tw;
    const int ab = kc * 65536 + ch;
#pragma unroll
    for (int j = 0; j < 16; ++j) {
        agg[ab + (n0 + j) * 1024]      = __builtin_amdgcn_exp2f(Aneg[j] * sdt);
        agg[ab + (32 + n0 + j) * 1024] = bA[j];
    }
}

__global__ __launch_bounds__(256) void ssm_k2(
    const float* __restrict__ agg, float* __restrict__ pref)
{
    const int T  = blockIdx.x * 256 + threadIdx.x;   // 32768 threads = (n, ch)
    const int ch = T & 1023;
    const int n  = T >> 10;
    const float* ap = agg + n * 1024 + ch;
    const float* bp = agg + (32 + n) * 1024 + ch;
    float*       pp = pref + n * 1024 + ch;

    float p = 0.0f;
    for (int k = 0; k < NKC; k += 8) {
        float a[8], bb[8];
#pragma unroll
        for (int i = 0; i < 8; ++i) {
            a[i]  = ap[(size_t)(k + i) * 65536];
            bb[i] = bp[(size_t)(k + i) * 65536];
        }
#pragma unroll
        for (int i = 0; i < 8; ++i) {
            pp[(size_t)(k + i) * 32768] = p;
            p = fmaf(a[i], p, bb[i]);
        }
    }
}

__global__ __launch_bounds__(512, 2) void ssm_k3(
    const float* __restrict__ dtp, const float* __restrict__ up,
    const float* __restrict__ Ap,  const float* __restrict__ Bp,
    const float* __restrict__ Cp,  const float* __restrict__ Dp,
    const float* __restrict__ pref, float* __restrict__ outp)
{
    __shared__ float ldt[SPB * 64];
    __shared__ float lu [SPB * 64];
    __shared__ float lB [SPB * 32];
    __shared__ float lC [SPB * 32];

    const int tid  = threadIdx.x;
    const int w    = tid >> 6;
    const int lane = tid & 63;
    const int tw   = w >> 1;
    const int dh   = w & 1;
    const int dlow = lane & 31;
    const int nh   = lane >> 5;
    const int bh   = blockIdx.x >> 5;
    const int kb   = blockIdx.x & 31;
    const int b = bh >> 3, hh = bh & 7;
    const int d  = dh * 32 + dlow;
    const int n0 = nh * 16;
    const int ch = bh * 64 + d;

    const int udbase = b * (S_LEN * 512) + kb * (SPB * 512) + hh * 64;
    const int bcbase = b * (S_LEN * 256) + kb * (SPB * 256) + hh * 32;

    // ---- stage slabs ----
    {
        int r = tid >> 4, c = tid & 15;
#pragma unroll
        for (int it = 0; it < 2; ++it, r += 32) {
            *(float4*)&ldt[r * 64 + c * 4] = *(const float4*)(dtp + udbase + r * 512 + c * 4);
            *(float4*)&lu [r * 64 + c * 4] = *(const float4*)(up  + udbase + r * 512 + c * 4);
        }
        const int rb = tid >> 3, cb = tid & 7;
        *(float4*)&lB[rb * 32 + cb * 4] = *(const float4*)(Bp + bcbase + rb * 256 + cb * 4);
        *(float4*)&lC[rb * 32 + cb * 4] = *(const float4*)(Cp + bcbase + rb * 256 + cb * 4);
    }

    float Aneg[16];
    {
        const float* Arow = Ap + (hh * D_DIM + d) * N_DIM + n0;
#pragma unroll
        for (int j = 0; j < 4; ++j) {
            float4 a4 = *(const float4*)(Arow + j * 4);
            Aneg[4*j+0] = NLOG2E * a4.x; Aneg[4*j+1] = NLOG2E * a4.y;
            Aneg[4*j+2] = NLOG2E * a4.z; Aneg[4*j+3] = NLOG2E * a4.w;
        }
    }

    // ---- entering state for this wave-pair's chunk (global loads overlap stage) ----
    float h[16];
    {
        const int kc = kb * 4 + tw;
        const int pb = kc * 32768 + ch;
#pragma unroll
        for (int j = 0; j < 16; ++j) h[j] = pref[pb + (n0 + j) * 1024];
    }

    __syncthreads();

    // ---- pass C: rescan 16 steps from LDS, combine n-halves, emit y ----
    const float Dv = Dp[hh];

#pragma unroll 2
    for (int t = 0; t < TW; ++t) {
        const int tt = tw * TW + t;
        const float dtv = ldt[tt * 64 + d];
        const float uv  = lu [tt * 64 + d];
        const float kk  = dtv * uv;
        float y0 = 0.0f, y1 = 0.0f, y2 = 0.0f, y3 = 0.0f;
#pragma unroll
        for (int j = 0; j < 4; ++j) {
            const float4 Bv = *(const float4*)&lB[tt * 32 + n0 + j * 4];
            const float4 Cv = *(const float4*)&lC[tt * 32 + n0 + j * 4];
#pragma unroll
            for (int q = 0; q < 4; ++q) {
                const int jn = j * 4 + q;
                const float bq = (q == 0) ? Bv.x : (q == 1) ? Bv.y : (q == 2) ? Bv.z : Bv.w;
                const float cq = (q == 0) ? Cv.x : (q == 1) ? Cv.y : (q == 2) ? Cv.z : Cv.w;
                const float e = __builtin_amdgcn_exp2f(dtv * Aneg[jn]);
                h[jn] = fmaf(e, h[jn], kk * bq);
                if (q == 0)      y0 = fmaf(h[jn], cq, y0);
                else if (q == 1) y1 = fmaf(h[jn], cq, y1);
                else if (q == 2) y2 = fmaf(h[jn], cq, y2);
                else             y3 = fmaf(h[jn], cq, y3);
            }
        }
        float y = (y0 + y1) + (y2 + y3);
        y += __shfl_xor(y, 32);
        if (nh == 0) outp[udbase + tt * 512 + d] = fmaf(Dv, uv, y);
    }
}

} // namespace

extern "C" void kernel_launch(void* const* d_in, const int* in_sizes, int n_in,
                              void* d_out, int out_size, void* d_ws, size_t ws_size,
                              hipStream_t stream)
{
    const float* u  = (const float*)d_in[0];
    const float* dt = (const float*)d_in[1];
    const float* A  = (const float*)d_in[2];
    const float* B  = (const float*)d_in[3];
    const float* C  = (const float*)d_in[4];
    const float* D  = (const float*)d_in[5];
    float* out = (float*)d_out;

    float* agg  = (float*)d_ws;                        // 128*64*1024 floats = 33.5 MB
    float* pref = agg + (size_t)NKC * 64 * 1024;       // 128*32*1024 floats = 16.8 MB

    ssm_k1<<<dim3(16 * NKB), dim3(512), 0, stream>>>(dt, u, A, B, agg);
    ssm_k2<<<dim3(128),      dim3(256), 0, stream>>>(agg, pref);
    ssm_k3<<<dim3(16 * NKB), dim3(512), 0, stream>>>(dt, u, A, B, C, D, pref, out);
}